// Round 2
// baseline (5232.549 us; speedup 1.0000x reference)
//
#include <hip/hip_runtime.h>
#include <hip/hip_bf16.h>
#include <math.h>
#include <stdint.h>

// ---- model dims ----
constexpr int VV  = 32000;
constexpr int DD  = 768;
constexpr int FFD = 3072;
constexpr int NH  = 12;
constexpr int DHD = 64;
constexpr int NL  = 4;
constexpr int NB  = 4;
constexpr int NT  = 1024;
constexpr int BT  = NB * NT;          // 4096
constexpr int QKVD = 3 * NH * DHD;    // 2304
constexpr float SCL = 0.125f;

typedef __attribute__((ext_vector_type(8))) short bf16x8;   // 8 bf16 = 4 VGPR
typedef __attribute__((ext_vector_type(4))) float f32x4;

__device__ inline unsigned short f2bf(float f) {  // RNE f32->bf16
  union { float f; uint32_t u; } v; v.f = f;
  return (unsigned short)((v.u + 0x7FFFu + ((v.u >> 16) & 1u)) >> 16);
}

// CK-style addrspace casts for global_load_lds (generic->AS via uintptr bounce)
#define GLB(p) ((const __attribute__((address_space(1))) void*)(uintptr_t)(p))
#define LDSP(p) ((__attribute__((address_space(3))) void*)(uint32_t)(uintptr_t)(p))

// ---------------- f32 -> bf16 bulk convert ----------------
__global__ __launch_bounds__(256) void conv_bf16_kernel(
    const float* __restrict__ in, unsigned short* __restrict__ out, int n) {
  int i = (blockIdx.x * 256 + threadIdx.x) * 4;
  if (i >= n) return;
  float4 v = *(const float4*)&in[i];
  ushort4 r;
  r.x = f2bf(v.x); r.y = f2bf(v.y); r.z = f2bf(v.z); r.w = f2bf(v.w);
  *(ushort4*)&out[i] = r;
}

// ---------------- RoPE cos/sin table [NT][32][2] (f64 trig, once) ----------------
__global__ __launch_bounds__(256) void rope_tab_kernel(float* __restrict__ tab) {
  int i = blockIdx.x * 256 + threadIdx.x;   // NT*32
  int j = i & 31, t = i >> 5;
  double invf = pow(10000.0, -(double)j / 32.0);
  double ang = (double)t * invf;
  tab[i * 2]     = (float)cos(ang);
  tab[i * 2 + 1] = (float)sin(ang);
}

// ---------------- fused embed gather + RMSNorm (f32 out) ----------------
__global__ __launch_bounds__(256) void embed_rms_kernel(
    const int* __restrict__ x, const float* __restrict__ ew,
    const float* __restrict__ w, float* __restrict__ h) {
  int row = blockIdx.x;
  const float* e = ew + (size_t)x[row] * DD;
  int t = threadIdx.x;
  float v0 = e[t], v1 = e[t + 256], v2 = e[t + 512];
  float ss = v0 * v0 + v1 * v1 + v2 * v2;
#pragma unroll
  for (int o = 32; o > 0; o >>= 1) ss += __shfl_down(ss, o, 64);
  __shared__ float red[4];
  if ((t & 63) == 0) red[t >> 6] = ss;
  __syncthreads();
  float tot = red[0] + red[1] + red[2] + red[3];
  float sc = rsqrtf(tot * (1.0f / DD) + 1e-6f);
  size_t base = (size_t)row * DD;
  h[base + t]       = v0 * sc * w[t];
  h[base + t + 256] = v1 * sc * w[t + 256];
  h[base + t + 512] = v2 * sc * w[t + 512];
}

// ---------------- RMSNorm f32 in -> bf16 out ----------------
__global__ __launch_bounds__(256) void rms_bf_kernel(
    const float* __restrict__ in, const float* __restrict__ w,
    unsigned short* __restrict__ out) {
  int row = blockIdx.x;
  const float* p = in + (size_t)row * DD;
  int t = threadIdx.x;
  float v0 = p[t], v1 = p[t + 256], v2 = p[t + 512];
  float ss = v0 * v0 + v1 * v1 + v2 * v2;
#pragma unroll
  for (int o = 32; o > 0; o >>= 1) ss += __shfl_down(ss, o, 64);
  __shared__ float red[4];
  if ((t & 63) == 0) red[t >> 6] = ss;
  __syncthreads();
  float tot = red[0] + red[1] + red[2] + red[3];
  float sc = rsqrtf(tot * (1.0f / DD) + 1e-6f);
  size_t base = (size_t)row * DD;
  out[base + t]       = f2bf(v0 * sc * w[t]);
  out[base + t + 256] = f2bf(v1 * sc * w[t + 256]);
  out[base + t + 512] = f2bf(v2 * sc * w[t + 512]);
}

// ---------------- bf16 MFMA GEMM: C[M,N](f32) = A[M,K]*W[N,K]^T (+C if ACC) ----
// m97 structure: 128x128 tile, BK=32, 256 thr / 4 waves, wave tile 64x64,
// linear LDS + global_load_lds(16B), 2 barriers per K-step.
template <int ACC>
__global__ __launch_bounds__(256) void gemm_bf16(
    const unsigned short* __restrict__ A, const unsigned short* __restrict__ W,
    float* __restrict__ C, int N, int K) {
  __shared__ __align__(16) short As[128 * 32];
  __shared__ __align__(16) short Bs[128 * 32];
  const int tid = threadIdx.x;
  const int lane = tid & 63, wv = tid >> 6;
  const int wr = wv >> 1, wc = wv & 1;
  const size_t arow0 = (size_t)blockIdx.y * 128;
  const size_t brow0 = (size_t)blockIdx.x * 128;

  f32x4 acc[4][4];
#pragma unroll
  for (int i = 0; i < 4; ++i)
#pragma unroll
    for (int j = 0; j < 4; ++j) acc[i][j] = (f32x4){0.f, 0.f, 0.f, 0.f};

  const int fr = lane & 15;          // fragment row (M/N within 16-block)
  const int kh = (lane >> 4) * 8;    // k-offset of this lane's 8 bf16

  for (int k0 = 0; k0 < K; k0 += 32) {
#pragma unroll
    for (int r = 0; r < 2; ++r) {
      int idx = r * 256 + tid;       // [0,512): 16B chunk id
      int row = idx >> 2, ks = (idx & 3) * 8;
      __builtin_amdgcn_global_load_lds(GLB(A + (arow0 + row) * K + k0 + ks),
                                       LDSP(As + idx * 8), 16, 0, 0);
      __builtin_amdgcn_global_load_lds(GLB(W + (brow0 + row) * K + k0 + ks),
                                       LDSP(Bs + idx * 8), 16, 0, 0);
    }
    __syncthreads();
    bf16x8 af[4], bfv[4];
#pragma unroll
    for (int i = 0; i < 4; ++i) {
      af[i]  = *(const bf16x8*)&As[(wr * 64 + i * 16 + fr) * 32 + kh];
      bfv[i] = *(const bf16x8*)&Bs[(wc * 64 + i * 16 + fr) * 32 + kh];
    }
#pragma unroll
    for (int i = 0; i < 4; ++i)
#pragma unroll
      for (int j = 0; j < 4; ++j)
        acc[i][j] = __builtin_amdgcn_mfma_f32_16x16x32_bf16(af[i], bfv[j],
                                                            acc[i][j], 0, 0, 0);
    __syncthreads();
  }
  // C/D layout (m89-verified): col = lane&15, row = (lane>>4)*4 + reg
  const int r4 = (lane >> 4) * 4;
#pragma unroll
  for (int i = 0; i < 4; ++i)
#pragma unroll
    for (int j = 0; j < 4; ++j) {
      float* cp = &C[(arow0 + wr * 64 + i * 16 + r4) * N +
                     brow0 + wc * 64 + j * 16 + fr];
#pragma unroll
      for (int q = 0; q < 4; ++q) {
        if (ACC) cp[(size_t)q * N] += acc[i][j][q];
        else     cp[(size_t)q * N]  = acc[i][j][q];
      }
    }
}

// ---------------- RoPE apply (in-place on q,k of qkv, f32) ----------------
__global__ __launch_bounds__(256) void rope_kernel(
    float* __restrict__ qkv, const float* __restrict__ tab) {
  int idx = blockIdx.x * 256 + threadIdx.x;   // BT*NH*32
  int j = idx & 31;
  int hh = (idx >> 5) % NH;
  int row = idx / (32 * NH);
  int t = row & (NT - 1);
  float c = tab[(t * 32 + j) * 2];
  float s = tab[(t * 32 + j) * 2 + 1];
  float* q = qkv + (size_t)row * QKVD + hh * DHD;
  float* k = q + DD;
  float q1 = q[j], q2 = q[j + 32];
  q[j]      = q1 * c - q2 * s;
  q[j + 32] = q2 * c + q1 * s;
  float k1 = k[j], k2 = k[j + 32];
  k[j]      = k1 * c - k2 * s;
  k[j + 32] = k2 * c + k1 * s;
}

// ---------------- causal attention (f32 compute, bf16 out), 16 q-rows/block ----
constexpr int QT = 16;
__global__ __launch_bounds__(256) void attn_kernel(
    const float* __restrict__ qkv, unsigned short* __restrict__ o) {
  __shared__ __align__(16) float Qs[QT][DHD];
  __shared__ __align__(16) float KVs[64][DHD + 4];
  __shared__ float Ss[QT][NT];

  int tq = blockIdx.x & 63;
  int bh = blockIdx.x >> 6;
  int b = bh / NH, hh = bh % NH;
  int q0 = tq * QT;
  const float* base = qkv + ((size_t)b * NT) * QKVD + hh * DHD;

  {
    int i = threadIdx.x;
    int qi = i >> 4, d4 = (i & 15) * 4;
    *(float4*)&Qs[qi][d4] = *(const float4*)&base[(size_t)(q0 + qi) * QKVD + d4];
  }
  int nkt = (q0 + QT + 63) >> 6;
  int qi = threadIdx.x >> 4;
  int x16 = threadIdx.x & 15;
  __syncthreads();

  for (int kt = 0; kt < nkt; ++kt) {
    int k0 = kt << 6;
#pragma unroll
    for (int i2 = 0; i2 < 4; ++i2) {
      int c = threadIdx.x + i2 * 256;
      int kk = c >> 4, d4 = (c & 15) * 4;
      *(float4*)&KVs[kk][d4] =
          *(const float4*)&base[(size_t)(k0 + kk) * QKVD + DD + d4];
    }
    __syncthreads();
#pragma unroll
    for (int cc = 0; cc < 4; ++cc) {
      int kj = x16 + cc * 16;
      float a = 0.f;
#pragma unroll
      for (int d = 0; d < DHD; d += 4) {
        float4 qv = *(const float4*)&Qs[qi][d];
        float4 kv = *(const float4*)&KVs[kj][d];
        a = fmaf(qv.x, kv.x, a); a = fmaf(qv.y, kv.y, a);
        a = fmaf(qv.z, kv.z, a); a = fmaf(qv.w, kv.w, a);
      }
      int kg = k0 + kj, qg = q0 + qi;
      Ss[qi][kg] = (kg <= qg) ? a * SCL : -INFINITY;
    }
    __syncthreads();
  }

  int ncol = nkt << 6;
  float m = -INFINITY;
  for (int j = x16; j < ncol; j += 16) m = fmaxf(m, Ss[qi][j]);
#pragma unroll
  for (int o2 = 8; o2 > 0; o2 >>= 1) m = fmaxf(m, __shfl_xor(m, o2, 16));
  float sum = 0.f;
  for (int j = x16; j < ncol; j += 16) {
    float e = expf(Ss[qi][j] - m);
    Ss[qi][j] = e;
    sum += e;
  }
#pragma unroll
  for (int o2 = 8; o2 > 0; o2 >>= 1) sum += __shfl_xor(sum, o2, 16);
  float inv = 1.f / sum;
  __syncthreads();

  float a0 = 0, a1 = 0, a2 = 0, a3 = 0;
  int d0 = x16 * 4;
  for (int kt = 0; kt < nkt; ++kt) {
    int k0 = kt << 6;
#pragma unroll
    for (int i2 = 0; i2 < 4; ++i2) {
      int c = threadIdx.x + i2 * 256;
      int kk = c >> 4, d4 = (c & 15) * 4;
      *(float4*)&KVs[kk][d4] =
          *(const float4*)&base[(size_t)(k0 + kk) * QKVD + 2 * DD + d4];
    }
    __syncthreads();
#pragma unroll 8
    for (int kk = 0; kk < 64; ++kk) {
      float p = Ss[qi][k0 + kk];
      float4 vv = *(const float4*)&KVs[kk][d0];
      a0 = fmaf(p, vv.x, a0); a1 = fmaf(p, vv.y, a1);
      a2 = fmaf(p, vv.z, a2); a3 = fmaf(p, vv.w, a3);
    }
    __syncthreads();
  }
  size_t ob = ((size_t)(b * NT + q0 + qi)) * DD + hh * DHD + d0;
  ushort4 r;
  r.x = f2bf(a0 * inv); r.y = f2bf(a1 * inv);
  r.z = f2bf(a2 * inv); r.w = f2bf(a3 * inv);
  *(ushort4*)&o[ob] = r;
}

// ---------------- silu(gate)*up -> bf16 ----------------
__global__ __launch_bounds__(256) void silu_mul_kernel(
    const float* __restrict__ gate, const float* __restrict__ up,
    unsigned short* __restrict__ out) {
  size_t i = ((size_t)blockIdx.x * 256 + threadIdx.x) * 4;
  float4 g = *(const float4*)&gate[i];
  float4 u = *(const float4*)&up[i];
  ushort4 r;
  r.x = f2bf(g.x / (1.f + expf(-g.x)) * u.x);
  r.y = f2bf(g.y / (1.f + expf(-g.y)) * u.y);
  r.z = f2bf(g.z / (1.f + expf(-g.z)) * u.z);
  r.w = f2bf(g.w / (1.f + expf(-g.w)) * u.w);
  *(ushort4*)&out[i] = r;
}

extern "C" void kernel_launch(void* const* d_in, const int* in_sizes, int n_in,
                              void* d_out, int out_size, void* d_ws, size_t ws_size,
                              hipStream_t stream) {
  const int*   x        = (const int*)d_in[0];
  const float* embed_w  = (const float*)d_in[1];
  const float* ln_in_w  = (const float*)d_in[2];
  const float* ln1_w    = (const float*)d_in[3];
  const float* qkv_w    = (const float*)d_in[4];
  const float* out_w    = (const float*)d_in[5];
  const float* ln2_w    = (const float*)d_in[6];
  const float* gate_w   = (const float*)d_in[7];
  const float* up_w     = (const float*)d_in[8];
  const float* down_w   = (const float*)d_in[9];
  const float* ln_out_w = (const float*)d_in[10];
  float* out = (float*)d_out;

  char* wp = (char*)d_ws;
  auto alloc = [&](size_t bytes) {
    char* p = wp; wp += (bytes + 255) & ~(size_t)255; return p;
  };
  float* h      = (float*)alloc((size_t)BT * DD * 4);
  float* qkv    = (float*)alloc((size_t)BT * QKVD * 4);
  float* gate   = (float*)alloc((size_t)BT * FFD * 4);
  float* up     = (float*)alloc((size_t)BT * FFD * 4);
  float* rtab   = (float*)alloc((size_t)NT * 32 * 2 * 4);
  unsigned short* g_bf    = (unsigned short*)alloc((size_t)BT * DD * 2);
  unsigned short* o_bf    = (unsigned short*)alloc((size_t)BT * DD * 2);
  unsigned short* act_bf  = (unsigned short*)alloc((size_t)BT * FFD * 2);
  unsigned short* qkvw_bf = (unsigned short*)alloc((size_t)NL * QKVD * DD * 2);
  unsigned short* outw_bf = (unsigned short*)alloc((size_t)NL * DD * DD * 2);
  unsigned short* gatew_bf= (unsigned short*)alloc((size_t)NL * FFD * DD * 2);
  unsigned short* upw_bf  = (unsigned short*)alloc((size_t)NL * FFD * DD * 2);
  unsigned short* downw_bf= (unsigned short*)alloc((size_t)NL * DD * FFD * 2);
  unsigned short* embw_bf = (unsigned short*)alloc((size_t)VV * DD * 2);

  auto conv = [&](const float* src, unsigned short* dst, size_t n) {
    conv_bf16_kernel<<<dim3((unsigned)((n / 4 + 255) / 256)), 256, 0, stream>>>(
        src, dst, (int)n);
  };
  rope_tab_kernel<<<(NT * 32) / 256, 256, 0, stream>>>(rtab);
  conv(qkv_w,  qkvw_bf,  (size_t)NL * QKVD * DD);
  conv(out_w,  outw_bf,  (size_t)NL * DD * DD);
  conv(gate_w, gatew_bf, (size_t)NL * FFD * DD);
  conv(up_w,   upw_bf,   (size_t)NL * FFD * DD);
  conv(down_w, downw_bf, (size_t)NL * DD * FFD);
  conv(embed_w, embw_bf, (size_t)VV * DD);

  embed_rms_kernel<<<BT, 256, 0, stream>>>(x, embed_w, ln_in_w, h);
  for (int l = 0; l < NL; ++l) {
    rms_bf_kernel<<<BT, 256, 0, stream>>>(h, ln1_w + l * DD, g_bf);
    gemm_bf16<0><<<dim3(QKVD / 128, BT / 128), 256, 0, stream>>>(
        g_bf, qkvw_bf + (size_t)l * QKVD * DD, qkv, QKVD, DD);
    rope_kernel<<<(BT * NH * 32) / 256, 256, 0, stream>>>(qkv, rtab);
    attn_kernel<<<NB * NH * (NT / QT), 256, 0, stream>>>(qkv, o_bf);
    gemm_bf16<1><<<dim3(DD / 128, BT / 128), 256, 0, stream>>>(
        o_bf, outw_bf + (size_t)l * DD * DD, h, DD, DD);
    rms_bf_kernel<<<BT, 256, 0, stream>>>(h, ln2_w + l * DD, g_bf);
    gemm_bf16<0><<<dim3(FFD / 128, BT / 128), 256, 0, stream>>>(
        g_bf, gatew_bf + (size_t)l * FFD * DD, gate, FFD, DD);
    gemm_bf16<0><<<dim3(FFD / 128, BT / 128), 256, 0, stream>>>(
        g_bf, upw_bf + (size_t)l * FFD * DD, up, FFD, DD);
    silu_mul_kernel<<<(BT * FFD / 4) / 256, 256, 0, stream>>>(gate, up, act_bf);
    gemm_bf16<1><<<dim3(DD / 128, BT / 128), 256, 0, stream>>>(
        act_bf, downw_bf + (size_t)l * DD * FFD, h, DD, FFD);
  }
  rms_bf_kernel<<<BT, 256, 0, stream>>>(h, ln_out_w, g_bf);
  gemm_bf16<0><<<dim3(VV / 128, BT / 128), 256, 0, stream>>>(
      g_bf, embw_bf, out, VV, DD);
  hipMemcpyAsync(out + (size_t)BT * VV, h, (size_t)BT * DD * sizeof(float),
                 hipMemcpyDeviceToDevice, stream);
}

// Round 3
// 2340.990 us; speedup vs baseline: 2.2352x; 2.2352x over previous
//
#include <hip/hip_runtime.h>
#include <hip/hip_bf16.h>
#include <math.h>
#include <stdint.h>

// ---- model dims ----
constexpr int VV  = 32000;
constexpr int DD  = 768;
constexpr int FFD = 3072;
constexpr int NH  = 12;
constexpr int DHD = 64;
constexpr int NL  = 4;
constexpr int NB  = 4;
constexpr int NT  = 1024;
constexpr int BT  = NB * NT;          // 4096
constexpr int QKVD = 3 * NH * DHD;    // 2304
constexpr float SCL = 0.125f;

typedef __attribute__((ext_vector_type(8))) short bf16x8;   // 8 bf16 = 4 VGPR
typedef __attribute__((ext_vector_type(4))) float f32x4;

__device__ inline unsigned short f2bf(float f) {  // RNE f32->bf16
  union { float f; uint32_t u; } v; v.f = f;
  return (unsigned short)((v.u + 0x7FFFu + ((v.u >> 16) & 1u)) >> 16);
}

// CK-style addrspace casts for global_load_lds
#define GLB(p) ((const __attribute__((address_space(1))) void*)(uintptr_t)(p))
#define LDSP(p) ((__attribute__((address_space(3))) void*)(uint32_t)(uintptr_t)(p))

// ---------------- f32 -> bf16 bulk convert ----------------
__global__ __launch_bounds__(256) void conv_bf16_kernel(
    const float* __restrict__ in, unsigned short* __restrict__ out, int n) {
  int i = (blockIdx.x * 256 + threadIdx.x) * 4;
  if (i >= n) return;
  float4 v = *(const float4*)&in[i];
  ushort4 r;
  r.x = f2bf(v.x); r.y = f2bf(v.y); r.z = f2bf(v.z); r.w = f2bf(v.w);
  *(ushort4*)&out[i] = r;
}

// ---------------- RoPE cos/sin table [NT][32][2] (f64 trig, once) ------------
__global__ __launch_bounds__(256) void rope_tab_kernel(float* __restrict__ tab) {
  int i = blockIdx.x * 256 + threadIdx.x;   // NT*32
  int j = i & 31, t = i >> 5;
  double invf = pow(10000.0, -(double)j / 32.0);
  double ang = (double)t * invf;
  tab[i * 2]     = (float)cos(ang);
  tab[i * 2 + 1] = (float)sin(ang);
}

// ---------------- fused embed gather + RMSNorm (f32 out) ----------------
__global__ __launch_bounds__(256) void embed_rms_kernel(
    const int* __restrict__ x, const float* __restrict__ ew,
    const float* __restrict__ w, float* __restrict__ h) {
  int row = blockIdx.x;
  const float* e = ew + (size_t)x[row] * DD;
  int t = threadIdx.x;
  float v0 = e[t], v1 = e[t + 256], v2 = e[t + 512];
  float ss = v0 * v0 + v1 * v1 + v2 * v2;
#pragma unroll
  for (int o = 32; o > 0; o >>= 1) ss += __shfl_down(ss, o, 64);
  __shared__ float red[4];
  if ((t & 63) == 0) red[t >> 6] = ss;
  __syncthreads();
  float tot = red[0] + red[1] + red[2] + red[3];
  float sc = rsqrtf(tot * (1.0f / DD) + 1e-6f);
  size_t base = (size_t)row * DD;
  h[base + t]       = v0 * sc * w[t];
  h[base + t + 256] = v1 * sc * w[t + 256];
  h[base + t + 512] = v2 * sc * w[t + 512];
}

// ---------------- RMSNorm f32 in -> bf16 out ----------------
__global__ __launch_bounds__(256) void rms_bf_kernel(
    const float* __restrict__ in, const float* __restrict__ w,
    unsigned short* __restrict__ out) {
  int row = blockIdx.x;
  const float* p = in + (size_t)row * DD;
  int t = threadIdx.x;
  float v0 = p[t], v1 = p[t + 256], v2 = p[t + 512];
  float ss = v0 * v0 + v1 * v1 + v2 * v2;
#pragma unroll
  for (int o = 32; o > 0; o >>= 1) ss += __shfl_down(ss, o, 64);
  __shared__ float red[4];
  if ((t & 63) == 0) red[t >> 6] = ss;
  __syncthreads();
  float tot = red[0] + red[1] + red[2] + red[3];
  float sc = rsqrtf(tot * (1.0f / DD) + 1e-6f);
  size_t base = (size_t)row * DD;
  out[base + t]       = f2bf(v0 * sc * w[t]);
  out[base + t + 256] = f2bf(v1 * sc * w[t + 256]);
  out[base + t + 512] = f2bf(v2 * sc * w[t + 512]);
}

// ---------------- bf16 MFMA GEMM (m97 structure, verified round 2) ------------
template <int ACC>
__global__ __launch_bounds__(256) void gemm_bf16(
    const unsigned short* __restrict__ A, const unsigned short* __restrict__ W,
    float* __restrict__ C, int N, int K) {
  __shared__ __align__(16) short As[128 * 32];
  __shared__ __align__(16) short Bs[128 * 32];
  const int tid = threadIdx.x;
  const int lane = tid & 63, wv = tid >> 6;
  const int wr = wv >> 1, wc = wv & 1;
  const size_t arow0 = (size_t)blockIdx.y * 128;
  const size_t brow0 = (size_t)blockIdx.x * 128;

  f32x4 acc[4][4];
#pragma unroll
  for (int i = 0; i < 4; ++i)
#pragma unroll
    for (int j = 0; j < 4; ++j) acc[i][j] = (f32x4){0.f, 0.f, 0.f, 0.f};

  const int fr = lane & 15;
  const int kh = (lane >> 4) * 8;

  for (int k0 = 0; k0 < K; k0 += 32) {
#pragma unroll
    for (int r = 0; r < 2; ++r) {
      int idx = r * 256 + tid;
      int row = idx >> 2, ks = (idx & 3) * 8;
      __builtin_amdgcn_global_load_lds(GLB(A + (arow0 + row) * K + k0 + ks),
                                       LDSP(As + idx * 8), 16, 0, 0);
      __builtin_amdgcn_global_load_lds(GLB(W + (brow0 + row) * K + k0 + ks),
                                       LDSP(Bs + idx * 8), 16, 0, 0);
    }
    __syncthreads();
    bf16x8 af[4], bfv[4];
#pragma unroll
    for (int i = 0; i < 4; ++i) {
      af[i]  = *(const bf16x8*)&As[(wr * 64 + i * 16 + fr) * 32 + kh];
      bfv[i] = *(const bf16x8*)&Bs[(wc * 64 + i * 16 + fr) * 32 + kh];
    }
#pragma unroll
    for (int i = 0; i < 4; ++i)
#pragma unroll
      for (int j = 0; j < 4; ++j)
        acc[i][j] = __builtin_amdgcn_mfma_f32_16x16x32_bf16(af[i], bfv[j],
                                                            acc[i][j], 0, 0, 0);
    __syncthreads();
  }
  const int r4 = (lane >> 4) * 4;
#pragma unroll
  for (int i = 0; i < 4; ++i)
#pragma unroll
    for (int j = 0; j < 4; ++j) {
      float* cp = &C[(arow0 + wr * 64 + i * 16 + r4) * N +
                     brow0 + wc * 64 + j * 16 + fr];
#pragma unroll
      for (int q = 0; q < 4; ++q) {
        if (ACC) cp[(size_t)q * N] += acc[i][j][q];
        else     cp[(size_t)q * N]  = acc[i][j][q];
      }
    }
}

// ---------------- RoPE apply: qkv f32 -> Qb(*SCL),Kb bf16 [bh][t][64] ---------
__global__ __launch_bounds__(256) void rope_qk_bf_kernel(
    const float* __restrict__ qkv, const float* __restrict__ tab,
    unsigned short* __restrict__ Qb, unsigned short* __restrict__ Kb) {
  int idx = blockIdx.x * 256 + threadIdx.x;   // BT*NH*32
  int j = idx & 31;
  int hh = (idx >> 5) % NH;
  int row = idx / (32 * NH);
  int t = row & (NT - 1);
  int b = row >> 10;
  float c = tab[(t * 32 + j) * 2];
  float s = tab[(t * 32 + j) * 2 + 1];
  const float* q = qkv + (size_t)row * QKVD + hh * DHD;
  const float* k = q + DD;
  float q1 = q[j], q2 = q[j + 32], k1 = k[j], k2 = k[j + 32];
  size_t qo = (((size_t)(b * NH + hh)) * NT + t) * 64;
  Qb[qo + j]      = f2bf((q1 * c - q2 * s) * SCL);
  Qb[qo + j + 32] = f2bf((q2 * c + q1 * s) * SCL);
  Kb[qo + j]      = f2bf(k1 * c - k2 * s);
  Kb[qo + j + 32] = f2bf(k2 * c + k1 * s);
}

// ---------------- V transpose: qkv f32 -> Vb bf16 [bh][d][t] ----------------
__global__ __launch_bounds__(256) void v_trans_kernel(
    const float* __restrict__ qkv, unsigned short* __restrict__ Vb) {
  __shared__ short Vt[64][72];
  int bh = blockIdx.x >> 4, tt = blockIdx.x & 15;
  int b = bh / NH, hh = bh % NH;
  int t0 = tt * 64;
#pragma unroll
  for (int it = 0; it < 4; ++it) {
    int idx = it * 256 + threadIdx.x;
    int t = idx >> 4, dq = (idx & 15) * 4;
    float4 v = *(const float4*)&qkv[((size_t)(b * NT) + t0 + t) * QKVD +
                                    2 * DD + hh * DHD + dq];
    Vt[dq + 0][t] = (short)f2bf(v.x);
    Vt[dq + 1][t] = (short)f2bf(v.y);
    Vt[dq + 2][t] = (short)f2bf(v.z);
    Vt[dq + 3][t] = (short)f2bf(v.w);
  }
  __syncthreads();
#pragma unroll
  for (int it = 0; it < 2; ++it) {
    int idx = it * 256 + threadIdx.x;
    int d = idx >> 3, to = (idx & 7) * 8;
    *(bf16x8*)&Vb[((size_t)bh * 64 + d) * NT + t0 + to] =
        *(const bf16x8*)&Vt[d][to];
  }
}

// ---------------- MFMA flash attention ----------------
// Block: 64 q-rows of one (b,h); 4 waves x 16 rows. KV tiles of 64.
// Fragment layouts identical to gemm_bf16 (verified): A row=lane&15,
// k=(lane>>4)*8+j ; C/D col=lane&15, row=(lane>>4)*4+reg.
__global__ __launch_bounds__(256) void attn_mfma_kernel(
    const unsigned short* __restrict__ Qb, const unsigned short* __restrict__ Kb,
    const unsigned short* __restrict__ Vb, unsigned short* __restrict__ o) {
  __shared__ __align__(16) short Ks[64][72];   // [kv][k]
  __shared__ __align__(16) short Vs[64][72];   // [d][kv]
  __shared__ __align__(16) short Ps[4][16][72];// per-wave P bounce [m][kv]

  const int tid = threadIdx.x;
  const int lane = tid & 63, w = tid >> 6;
  const int tq = blockIdx.x & 15;
  const int bh = blockIdx.x >> 4;
  const int b = bh / NH, hh = bh % NH;
  const int q0 = tq * 64;

  const unsigned short* Qp = Qb + (size_t)bh * NT * 64;
  const unsigned short* Kp = Kb + (size_t)bh * NT * 64;
  const unsigned short* Vp = Vb + (size_t)bh * 64 * NT;

  const int fr = lane & 15;
  const int kh = (lane >> 4) * 8;

  bf16x8 qf[2];
#pragma unroll
  for (int f = 0; f < 2; ++f)
    qf[f] = *(const bf16x8*)&Qp[(size_t)(q0 + w * 16 + fr) * 64 + f * 32 + kh];

  f32x4 Oacc[4];
#pragma unroll
  for (int i = 0; i < 4; ++i) Oacc[i] = (f32x4){0.f, 0.f, 0.f, 0.f};
  float mrow[4] = {-INFINITY, -INFINITY, -INFINITY, -INFINITY};
  float lrow[4] = {0.f, 0.f, 0.f, 0.f};

  for (int kt = 0; kt <= tq; ++kt) {
    const int kv0 = kt * 64;
    // cooperative stage: K [64][64] and V^T [64][64] (16B chunks, padded LDS)
#pragma unroll
    for (int it = 0; it < 2; ++it) {
      int idx = it * 256 + tid;
      int r = idx >> 3, co = (idx & 7) * 8;
      *(bf16x8*)&Ks[r][co] = *(const bf16x8*)&Kp[(size_t)(kv0 + r) * 64 + co];
      *(bf16x8*)&Vs[r][co] = *(const bf16x8*)&Vp[(size_t)r * NT + kv0 + co];
    }
    __syncthreads();

    // S = Q K^T  (16 x 64 per wave)
    f32x4 sa[4];
#pragma unroll
    for (int nb = 0; nb < 4; ++nb) {
      sa[nb] = (f32x4){0.f, 0.f, 0.f, 0.f};
#pragma unroll
      for (int f = 0; f < 2; ++f) {
        bf16x8 kf = *(const bf16x8*)&Ks[nb * 16 + fr][f * 32 + kh];
        sa[nb] = __builtin_amdgcn_mfma_f32_16x16x32_bf16(qf[f], kf, sa[nb], 0, 0, 0);
      }
    }
    // causal mask: only diagonal tile needs it
    if (kt == tq) {
#pragma unroll
      for (int nb = 0; nb < 4; ++nb) {
        int col = kv0 + nb * 16 + fr;
#pragma unroll
        for (int q = 0; q < 4; ++q) {
          int qr = q0 + w * 16 + (lane >> 4) * 4 + q;
          if (col > qr) sa[nb][q] = -INFINITY;
        }
      }
    }
    // online softmax (rows live in 16-lane groups)
    float sc[4];
#pragma unroll
    for (int q = 0; q < 4; ++q) {
      float t2 = fmaxf(fmaxf(sa[0][q], sa[1][q]), fmaxf(sa[2][q], sa[3][q]));
#pragma unroll
      for (int o2 = 8; o2 > 0; o2 >>= 1) t2 = fmaxf(t2, __shfl_xor(t2, o2, 16));
      float mn = fmaxf(mrow[q], t2);
      sc[q] = expf(mrow[q] - mn);
      mrow[q] = mn;
      float p0 = expf(sa[0][q] - mn), p1 = expf(sa[1][q] - mn);
      float p2 = expf(sa[2][q] - mn), p3 = expf(sa[3][q] - mn);
      sa[0][q] = p0; sa[1][q] = p1; sa[2][q] = p2; sa[3][q] = p3;
      float r2 = p0 + p1 + p2 + p3;
#pragma unroll
      for (int o2 = 8; o2 > 0; o2 >>= 1) r2 += __shfl_xor(r2, o2, 16);
      lrow[q] = lrow[q] * sc[q] + r2;
    }
#pragma unroll
    for (int nb = 0; nb < 4; ++nb)
#pragma unroll
      for (int q = 0; q < 4; ++q) Oacc[nb][q] *= sc[q];
    // P -> LDS (C-layout write), re-read as A-fragments
#pragma unroll
    for (int nb = 0; nb < 4; ++nb)
#pragma unroll
      for (int q = 0; q < 4; ++q)
        Ps[w][(lane >> 4) * 4 + q][nb * 16 + fr] = (short)f2bf(sa[nb][q]);
    bf16x8 pf[2];
#pragma unroll
    for (int f = 0; f < 2; ++f)
      pf[f] = *(const bf16x8*)&Ps[w][fr][f * 32 + kh];
    // O += P V  (V^T staged: B-frag n=d, k=kv)
#pragma unroll
    for (int nb2 = 0; nb2 < 4; ++nb2)
#pragma unroll
      for (int f = 0; f < 2; ++f) {
        bf16x8 vf = *(const bf16x8*)&Vs[nb2 * 16 + fr][f * 32 + kh];
        Oacc[nb2] = __builtin_amdgcn_mfma_f32_16x16x32_bf16(pf[f], vf, Oacc[nb2], 0, 0, 0);
      }
    __syncthreads();
  }
  // epilogue: normalize, write bf16
#pragma unroll
  for (int q = 0; q < 4; ++q) {
    float inv = 1.f / lrow[q];
    int qr = q0 + w * 16 + (lane >> 4) * 4 + q;
    size_t ob = ((size_t)(b * NT) + qr) * DD + hh * DHD;
#pragma unroll
    for (int nb2 = 0; nb2 < 4; ++nb2)
      o[ob + nb2 * 16 + fr] = f2bf(Oacc[nb2][q] * inv);
  }
}

// ---------------- silu(gate)*up -> bf16 ----------------
__global__ __launch_bounds__(256) void silu_mul_kernel(
    const float* __restrict__ gate, const float* __restrict__ up,
    unsigned short* __restrict__ out) {
  size_t i = ((size_t)blockIdx.x * 256 + threadIdx.x) * 4;
  float4 g = *(const float4*)&gate[i];
  float4 u = *(const float4*)&up[i];
  ushort4 r;
  r.x = f2bf(g.x / (1.f + expf(-g.x)) * u.x);
  r.y = f2bf(g.y / (1.f + expf(-g.y)) * u.y);
  r.z = f2bf(g.z / (1.f + expf(-g.z)) * u.z);
  r.w = f2bf(g.w / (1.f + expf(-g.w)) * u.w);
  *(ushort4*)&out[i] = r;
}

extern "C" void kernel_launch(void* const* d_in, const int* in_sizes, int n_in,
                              void* d_out, int out_size, void* d_ws, size_t ws_size,
                              hipStream_t stream) {
  const int*   x        = (const int*)d_in[0];
  const float* embed_w  = (const float*)d_in[1];
  const float* ln_in_w  = (const float*)d_in[2];
  const float* ln1_w    = (const float*)d_in[3];
  const float* qkv_w    = (const float*)d_in[4];
  const float* out_w    = (const float*)d_in[5];
  const float* ln2_w    = (const float*)d_in[6];
  const float* gate_w   = (const float*)d_in[7];
  const float* up_w     = (const float*)d_in[8];
  const float* down_w   = (const float*)d_in[9];
  const float* ln_out_w = (const float*)d_in[10];
  float* out = (float*)d_out;

  char* wp = (char*)d_ws;
  auto alloc = [&](size_t bytes) {
    char* p = wp; wp += (bytes + 255) & ~(size_t)255; return p;
  };
  float* h      = (float*)alloc((size_t)BT * DD * 4);
  float* qkv    = (float*)alloc((size_t)BT * QKVD * 4);
  float* gate   = (float*)alloc((size_t)BT * FFD * 4);
  float* up     = (float*)alloc((size_t)BT * FFD * 4);
  float* rtab   = (float*)alloc((size_t)NT * 32 * 2 * 4);
  unsigned short* g_bf    = (unsigned short*)alloc((size_t)BT * DD * 2);
  unsigned short* o_bf    = (unsigned short*)alloc((size_t)BT * DD * 2);
  unsigned short* act_bf  = (unsigned short*)alloc((size_t)BT * FFD * 2);
  unsigned short* Qb      = (unsigned short*)alloc((size_t)NB * NH * NT * 64 * 2);
  unsigned short* Kb      = (unsigned short*)alloc((size_t)NB * NH * NT * 64 * 2);
  unsigned short* Vb      = (unsigned short*)alloc((size_t)NB * NH * NT * 64 * 2);
  unsigned short* qkvw_bf = (unsigned short*)alloc((size_t)NL * QKVD * DD * 2);
  unsigned short* outw_bf = (unsigned short*)alloc((size_t)NL * DD * DD * 2);
  unsigned short* gatew_bf= (unsigned short*)alloc((size_t)NL * FFD * DD * 2);
  unsigned short* upw_bf  = (unsigned short*)alloc((size_t)NL * FFD * DD * 2);
  unsigned short* downw_bf= (unsigned short*)alloc((size_t)NL * DD * FFD * 2);
  unsigned short* embw_bf = (unsigned short*)alloc((size_t)VV * DD * 2);

  auto conv = [&](const float* src, unsigned short* dst, size_t n) {
    conv_bf16_kernel<<<dim3((unsigned)((n / 4 + 255) / 256)), 256, 0, stream>>>(
        src, dst, (int)n);
  };
  rope_tab_kernel<<<(NT * 32) / 256, 256, 0, stream>>>(rtab);
  conv(qkv_w,  qkvw_bf,  (size_t)NL * QKVD * DD);
  conv(out_w,  outw_bf,  (size_t)NL * DD * DD);
  conv(gate_w, gatew_bf, (size_t)NL * FFD * DD);
  conv(up_w,   upw_bf,   (size_t)NL * FFD * DD);
  conv(down_w, downw_bf, (size_t)NL * DD * FFD);
  conv(embed_w, embw_bf, (size_t)VV * DD);

  embed_rms_kernel<<<BT, 256, 0, stream>>>(x, embed_w, ln_in_w, h);
  for (int l = 0; l < NL; ++l) {
    rms_bf_kernel<<<BT, 256, 0, stream>>>(h, ln1_w + l * DD, g_bf);
    gemm_bf16<0><<<dim3(QKVD / 128, BT / 128), 256, 0, stream>>>(
        g_bf, qkvw_bf + (size_t)l * QKVD * DD, qkv, QKVD, DD);
    rope_qk_bf_kernel<<<(BT * NH * 32) / 256, 256, 0, stream>>>(qkv, rtab, Qb, Kb);
    v_trans_kernel<<<NB * NH * (NT / 64), 256, 0, stream>>>(qkv, Vb);
    attn_mfma_kernel<<<NB * NH * (NT / 64), 256, 0, stream>>>(Qb, Kb, Vb, o_bf);
    gemm_bf16<1><<<dim3(DD / 128, BT / 128), 256, 0, stream>>>(
        o_bf, outw_bf + (size_t)l * DD * DD, h, DD, DD);
    rms_bf_kernel<<<BT, 256, 0, stream>>>(h, ln2_w + l * DD, g_bf);
    gemm_bf16<0><<<dim3(FFD / 128, BT / 128), 256, 0, stream>>>(
        g_bf, gatew_bf + (size_t)l * FFD * DD, gate, FFD, DD);
    gemm_bf16<0><<<dim3(FFD / 128, BT / 128), 256, 0, stream>>>(
        g_bf, upw_bf + (size_t)l * FFD * DD, up, FFD, DD);
    silu_mul_kernel<<<(BT * FFD / 4) / 256, 256, 0, stream>>>(gate, up, act_bf);
    gemm_bf16<1><<<dim3(DD / 128, BT / 128), 256, 0, stream>>>(
        act_bf, downw_bf + (size_t)l * DD * FFD, h, DD, FFD);
  }
  rms_bf_kernel<<<BT, 256, 0, stream>>>(h, ln_out_w, g_bf);
  gemm_bf16<0><<<dim3(VV / 128, BT / 128), 256, 0, stream>>>(
      g_bf, embw_bf, out, VV, DD);
  hipMemcpyAsync(out + (size_t)BT * VV, h, (size_t)BT * DD * sizeof(float),
                 hipMemcpyDeviceToDevice, stream);
}